// Round 2
// baseline (434.871 us; speedup 1.0000x reference)
//
#include <hip/hip_runtime.h>
#include <hip/hip_bf16.h>
#include <cstdint>

// GRU: B=2048, T=256, F=64, H=32. fp32 in/out.
// Phase 1 (proj_mfma): xg = x @ W_ih^T + b_ih via bf16 MFMA with hi/lo split
//   (fp32-quality products); xg stored bf16 in d_ws (96 MB). No LDS.
// Phase 2 (gru_scan): 1 wave per batch, thread=(h, k-half); W_hh in VGPRs;
//   h broadcast via 16 bpermutes; partials combined with shfl_xor(32);
//   xg prefetched 2 steps ahead. Head fused.

#define BATCH 2048
#define TSEQ  256
#define FDIM  64
#define G3    96
#define BT    (BATCH * TSEQ)

typedef __attribute__((ext_vector_type(8))) short bf16x8;
typedef __attribute__((ext_vector_type(4))) float f32x4;

__device__ __forceinline__ short f2bf(float f) {
    union { float f; unsigned u; } v; v.f = f;
    unsigned r = (v.u + 0x7fffu + ((v.u >> 16) & 1u)) >> 16;
    return (short)r;
}
__device__ __forceinline__ float bf2f(unsigned short s) {
    union { unsigned u; float f; } v; v.u = ((unsigned)s) << 16;
    return v.f;
}

// ---------------- Phase 1: projection via MFMA (hi/lo bf16) -----------------
// 512 blocks x 256 threads = 2048 waves; wave handles 16 groups of 16 rows.
// Per 16x16 C tile: col = lane&15 (gate), row = (lane>>4)*4 + reg.
// A[m][k]: m = lane&15, k = (lane>>4)*8 + j.  B[k][n]: n = lane&15, same k.
__global__ __launch_bounds__(256, 2)
void proj_mfma(const float* __restrict__ x, const float* __restrict__ W_ih,
               const float* __restrict__ b_ih, unsigned short* __restrict__ xg)
{
    const int tid  = threadIdx.x;
    const int wave = (blockIdx.x << 2) + (tid >> 6);
    const int lane = tid & 63;
    const int m    = lane & 15;        // A row / B col / C col
    const int q    = lane >> 4;        // quad

    // --- W_ih -> B fragments (6 n-tiles x 2 k-steps, hi/lo), in registers ---
    bf16x8 bh[12], bl[12];
    #pragma unroll
    for (int nt = 0; nt < 6; ++nt)
        #pragma unroll
        for (int s = 0; s < 2; ++s) {
            const float* wp = W_ih + (nt * 16 + m) * 64 + s * 32 + q * 8;
            bf16x8 h8, l8;
            #pragma unroll
            for (int j = 0; j < 8; ++j) {
                float w  = wp[j];
                short hh = f2bf(w);
                h8[j] = hh;
                l8[j] = f2bf(w - bf2f((unsigned short)hh));
            }
            bh[nt * 2 + s] = h8;
            bl[nt * 2 + s] = l8;
        }
    float bias[6];
    #pragma unroll
    for (int nt = 0; nt < 6; ++nt) bias[nt] = b_ih[nt * 16 + m];

    // --- 16 row-groups per wave, software-pipelined A loads ---
    long g0 = (long)wave * 16;
    const float* ap = x + (g0 * 16 + m) * 64 + q * 8;   // this lane's base
    float4 nxt0 = ((const float4*)ap)[0];
    float4 nxt1 = ((const float4*)ap)[1];
    float4 nxt2 = ((const float4*)(ap + 32))[0];
    float4 nxt3 = ((const float4*)(ap + 32))[1];

    for (int i = 0; i < 16; ++i) {
        float4 a0 = nxt0, a1 = nxt1, a2 = nxt2, a3 = nxt3;
        if (i + 1 < 16) {
            const float* np = ap + (i + 1) * 16 * 64;
            nxt0 = ((const float4*)np)[0];
            nxt1 = ((const float4*)np)[1];
            nxt2 = ((const float4*)(np + 32))[0];
            nxt3 = ((const float4*)(np + 32))[1];
        }
        // hi/lo A fragments for the 2 k-steps
        float av[16] = {a0.x,a0.y,a0.z,a0.w, a1.x,a1.y,a1.z,a1.w,
                        a2.x,a2.y,a2.z,a2.w, a3.x,a3.y,a3.z,a3.w};
        bf16x8 ah[2], al[2];
        #pragma unroll
        for (int s = 0; s < 2; ++s)
            #pragma unroll
            for (int j = 0; j < 8; ++j) {
                float v  = av[s * 8 + j];
                short hh = f2bf(v);
                ah[s][j] = hh;
                al[s][j] = f2bf(v - bf2f((unsigned short)hh));
            }

        f32x4 acc[6];
        #pragma unroll
        for (int nt = 0; nt < 6; ++nt) acc[nt] = (f32x4){0.f, 0.f, 0.f, 0.f};

        #pragma unroll
        for (int s = 0; s < 2; ++s)
            #pragma unroll
            for (int nt = 0; nt < 6; ++nt) {
                acc[nt] = __builtin_amdgcn_mfma_f32_16x16x32_bf16(ah[s], bh[nt*2+s], acc[nt], 0, 0, 0);
                acc[nt] = __builtin_amdgcn_mfma_f32_16x16x32_bf16(al[s], bh[nt*2+s], acc[nt], 0, 0, 0);
                acc[nt] = __builtin_amdgcn_mfma_f32_16x16x32_bf16(ah[s], bl[nt*2+s], acc[nt], 0, 0, 0);
            }

        // epilogue: bias + bf16 store.  row = row0 + q*4 + reg, col = nt*16 + m
        long row0 = (g0 + i) * 16;
        #pragma unroll
        for (int reg = 0; reg < 4; ++reg) {
            unsigned short* dst = xg + (row0 + q * 4 + reg) * G3 + m;
            #pragma unroll
            for (int nt = 0; nt < 6; ++nt)
                dst[nt * 16] = (unsigned short)f2bf(acc[nt][reg] + bias[nt]);
        }
    }
}

// ---------------- Phase 2: recurrence + head --------------------------------
// 512 blocks x 256 threads; 1 wave per batch; lane = h + 32*ks (k-split x2).
__global__ __launch_bounds__(256, 2)
void gru_scan(const unsigned short* __restrict__ xg,
              const float* __restrict__ W_hh, const float* __restrict__ b_hh,
              const float* __restrict__ W_head, const float* __restrict__ b_head,
              float* __restrict__ out)
{
    const int tid = threadIdx.x;
    const int h   = tid & 31;
    const int ks  = (tid >> 5) & 1;
    const int k0  = ks * 16;
    const long b  = (long)blockIdx.x * 4 + (tid >> 6);

    float wr[16], wz[16], wn[16];
    #pragma unroll
    for (int j = 0; j < 16; ++j) {
        wr[j] = W_hh[(h     ) * 32 + k0 + j];
        wz[j] = W_hh[(32 + h) * 32 + k0 + j];
        wn[j] = W_hh[(64 + h) * 32 + k0 + j];
    }
    const float bhr = b_hh[h], bhz = b_hh[32 + h], bhn = b_hh[64 + h];

    const unsigned short* xp = xg + b * (long)(TSEQ * G3);

    // 2-deep prefetch ring
    float xr[2], xz[2], xn[2];
    #pragma unroll
    for (int t = 0; t < 2; ++t) {
        const unsigned short* qp = xp + t * G3;
        xr[t] = bf2f(qp[h]); xz[t] = bf2f(qp[32 + h]); xn[t] = bf2f(qp[64 + h]);
    }

    float h_own = 0.f;
    for (int t = 0; t < TSEQ; ++t) {
        const int cur = t & 1;
        float cxr = xr[cur], cxz = xz[cur], cxn = xn[cur];
        if (t + 2 < TSEQ) {
            const unsigned short* qp = xp + (t + 2) * G3;
            xr[cur] = bf2f(qp[h]); xz[cur] = bf2f(qp[32 + h]); xn[cur] = bf2f(qp[64 + h]);
        }

        float pr = 0.f, pz = 0.f, pn = 0.f;
        #pragma unroll
        for (int j = 0; j < 16; ++j) {
            float hv = __shfl(h_own, k0 + j, 64);   // h[k0+j] lives in lane k0+j
            pr += wr[j] * hv;
            pz += wz[j] * hv;
            pn += wn[j] * hv;
        }
        pr += __shfl_xor(pr, 32, 64);
        pz += __shfl_xor(pz, 32, 64);
        pn += __shfl_xor(pn, 32, 64);

        float r = 1.f / (1.f + __expf(-(cxr + pr + bhr)));
        float z = 1.f / (1.f + __expf(-(cxz + pz + bhz)));
        float a = cxn + r * (pn + bhn);
        float e = __expf(-2.f * fabsf(a));
        float th = copysignf((1.f - e) / (1.f + e), a);
        h_own = (1.f - z) * th + z * h_own;
    }

    // head: both k-halves hold identical h_own; count lower half only
    float v = (ks == 0) ? h_own * W_head[h] : 0.f;
    #pragma unroll
    for (int s = 32; s >= 1; s >>= 1) v += __shfl_xor(v, s, 64);
    if ((tid & 63) == 0) out[b] = 1.f / (1.f + __expf(-(v + b_head[0])));
}

extern "C" void kernel_launch(void* const* d_in, const int* in_sizes, int n_in,
                              void* d_out, int out_size, void* d_ws, size_t ws_size,
                              hipStream_t stream)
{
    const float* x      = (const float*)d_in[0];
    const float* W_ih   = (const float*)d_in[1];
    const float* W_hh   = (const float*)d_in[2];
    const float* b_ih   = (const float*)d_in[3];
    const float* b_hh   = (const float*)d_in[4];
    const float* W_head = (const float*)d_in[5];
    const float* b_head = (const float*)d_in[6];
    float* out = (float*)d_out;

    unsigned short* xg = (unsigned short*)d_ws;   // bf16 xg, 96 MB

    proj_mfma<<<512, 256, 0, stream>>>(x, W_ih, b_ih, xg);
    gru_scan<<<512, 256, 0, stream>>>(xg, W_hh, b_hh, W_head, b_head, out);
}

// Round 3
// 398.333 us; speedup vs baseline: 1.0917x; 1.0917x over previous
//
#include <hip/hip_runtime.h>
#include <hip/hip_bf16.h>
#include <cstdint>

// GRU: B=2048, T=256, F=64, H=32. fp32 in/out.
// Phase 1 (proj_mfma32): xg = x@W_ih^T + b_ih via 32x32x16 bf16 MFMA, hi/lo
//   split for fp32-quality products. C layout col=lane&31 -> stores are full
//   64B lines. xg bf16 [row][96] in d_ws.
// Phase 2 (gru_scan): 1 wave per batch. Lanes 0-31 = r-rows, 32-63 = z-rows
//   (one FMA stream covers both); n computed redundantly in both halves.
//   h broadcast via v_readlane (VALU pipe, no LDS) -- kills the bpermute wall.

#define BATCH 2048
#define TSEQ  256
#define G3    96

typedef __attribute__((ext_vector_type(8)))  short bf16x8;
typedef __attribute__((ext_vector_type(16))) float f32x16;

__device__ __forceinline__ short f2bf(float f) {
    union { float f; unsigned u; } v; v.f = f;
    unsigned r = (v.u + 0x7fffu + ((v.u >> 16) & 1u)) >> 16;
    return (short)r;
}
__device__ __forceinline__ float bf2f(unsigned short s) {
    union { unsigned u; float f; } v; v.u = ((unsigned)s) << 16;
    return v.f;
}

// ---------------- Phase 1: projection via 32x32x16 MFMA ---------------------
// 512 blocks x 256 thr = 2048 waves; wave does 8 iters of 32 rows x 96 gates.
// A[m][k]: m=lane&31, k=(lane>>5)*8+j.  B[k][n]: n=lane&31, same k.
// C: col=lane&31, row=(reg&3)+8*(reg>>2)+4*(lane>>5).
__global__ __launch_bounds__(256, 2)
void proj_mfma32(const float* __restrict__ x, const float* __restrict__ W_ih,
                 const float* __restrict__ b_ih, unsigned short* __restrict__ xg)
{
    const int tid  = threadIdx.x;
    const int wave = (blockIdx.x << 2) + (tid >> 6);
    const int lane = tid & 63;
    const int n    = lane & 31;
    const int half = lane >> 5;            // k-group: k = half*8 + j

    // B fragments: 3 n-tiles x 4 k-steps, hi & lo (96 VGPR)
    bf16x8 Bh[12], Bl[12];
    #pragma unroll
    for (int nt = 0; nt < 3; ++nt)
        #pragma unroll
        for (int ks = 0; ks < 4; ++ks) {
            const float* wp = W_ih + (nt * 32 + n) * 64 + ks * 16 + half * 8;
            bf16x8 h8, l8;
            #pragma unroll
            for (int j = 0; j < 8; ++j) {
                float w  = wp[j];
                short hh = f2bf(w);
                h8[j] = hh;
                l8[j] = f2bf(w - bf2f((unsigned short)hh));
            }
            Bh[nt * 4 + ks] = h8;
            Bl[nt * 4 + ks] = l8;
        }
    float bias[3];
    #pragma unroll
    for (int nt = 0; nt < 3; ++nt) bias[nt] = b_ih[nt * 32 + n];

    const long it0 = (long)wave * 8;
    // this lane's A base: row = row0 + n, cols half*8 .. half*8+7 (+16*ks)
    const float* ap = x + (it0 * 32 + n) * 64 + half * 8;

    // prefetch iter 0: 4 k-steps x 2 float4
    float4 raw[8];
    #pragma unroll
    for (int ks = 0; ks < 4; ++ks) {
        raw[ks * 2 + 0] = ((const float4*)(ap + ks * 16))[0];
        raw[ks * 2 + 1] = ((const float4*)(ap + ks * 16))[1];
    }

    for (int i = 0; i < 8; ++i) {
        float4 cur[8];
        #pragma unroll
        for (int u = 0; u < 8; ++u) cur[u] = raw[u];
        if (i + 1 < 8) {
            const float* np = ap + (i + 1) * 32 * 64;
            #pragma unroll
            for (int ks = 0; ks < 4; ++ks) {
                raw[ks * 2 + 0] = ((const float4*)(np + ks * 16))[0];
                raw[ks * 2 + 1] = ((const float4*)(np + ks * 16))[1];
            }
        }

        f32x16 acc[3];
        #pragma unroll
        for (int nt = 0; nt < 3; ++nt)
            #pragma unroll
            for (int r = 0; r < 16; ++r) acc[nt][r] = 0.f;

        #pragma unroll
        for (int ks = 0; ks < 4; ++ks) {
            float av[8] = {cur[ks*2].x,  cur[ks*2].y,  cur[ks*2].z,  cur[ks*2].w,
                           cur[ks*2+1].x,cur[ks*2+1].y,cur[ks*2+1].z,cur[ks*2+1].w};
            bf16x8 Ah, Al;
            #pragma unroll
            for (int j = 0; j < 8; ++j) {
                short hh = f2bf(av[j]);
                Ah[j] = hh;
                Al[j] = f2bf(av[j] - bf2f((unsigned short)hh));
            }
            #pragma unroll
            for (int nt = 0; nt < 3; ++nt) {
                acc[nt] = __builtin_amdgcn_mfma_f32_32x32x16_bf16(Ah, Bh[nt*4+ks], acc[nt], 0, 0, 0);
                acc[nt] = __builtin_amdgcn_mfma_f32_32x32x16_bf16(Al, Bh[nt*4+ks], acc[nt], 0, 0, 0);
                acc[nt] = __builtin_amdgcn_mfma_f32_32x32x16_bf16(Ah, Bl[nt*4+ks], acc[nt], 0, 0, 0);
            }
        }

        // store: full 64B lines (32 lanes x 2B contiguous per half)
        const long row0 = (it0 + i) * 32;
        #pragma unroll
        for (int nt = 0; nt < 3; ++nt)
            #pragma unroll
            for (int reg = 0; reg < 16; ++reg) {
                int row = (reg & 3) + 8 * (reg >> 2) + 4 * half;
                xg[(size_t)(row0 + row) * G3 + nt * 32 + n] =
                    (unsigned short)f2bf(acc[nt][reg] + bias[nt]);
            }
    }
}

// ---------------- Phase 2: recurrence + head --------------------------------
// 512 blocks x 256 thr; wave = 1 batch. lane<32: W_r row lane; lane>=32: W_z
// row lane. Both halves hold W_n row (lane&31). h broadcast via v_readlane.
__global__ __launch_bounds__(256, 2)
void gru_scan(const unsigned short* __restrict__ xg,
              const float* __restrict__ W_hh, const float* __restrict__ b_hh,
              const float* __restrict__ W_head, const float* __restrict__ b_head,
              float* __restrict__ out)
{
    const int tid  = threadIdx.x;
    const int lane = tid & 63;
    const int h    = lane & 31;
    const long b   = (long)blockIdx.x * 4 + (tid >> 6);

    // weights: wrz = W_hh row `lane` (r rows 0-31 | z rows 32-63); wn = row 64+h
    float wrz[32], wn[32];
    #pragma unroll
    for (int c = 0; c < 8; ++c) {
        float4 v = ((const float4*)(W_hh + lane * 32))[c];
        wrz[c*4+0] = v.x; wrz[c*4+1] = v.y; wrz[c*4+2] = v.z; wrz[c*4+3] = v.w;
        float4 u = ((const float4*)(W_hh + (64 + h) * 32))[c];
        wn[c*4+0] = u.x; wn[c*4+1] = u.y; wn[c*4+2] = u.z; wn[c*4+3] = u.w;
    }
    const float brz = b_hh[lane];          // r or z bias
    const float bn  = b_hh[64 + h];

    const unsigned short* xp = xg + b * (long)(TSEQ * G3);

    // 2-deep prefetch ring: per slot {xrz (gate=lane), xn (gate=64+h)}
    float pxrz[2], pxn[2];
    #pragma unroll
    for (int t = 0; t < 2; ++t) {
        const unsigned short* q = xp + t * G3;
        pxrz[t] = bf2f(q[lane]);
        pxn[t]  = bf2f(q[64 + h]);
    }

    const float LOG2E = 1.44269504f;
    float hstate = 0.f;                    // valid in lanes 0-31

    for (int t = 0; t < TSEQ; ++t) {
        const int cur = t & 1;
        float cxrz = pxrz[cur], cxn = pxn[cur];
        if (t + 2 < TSEQ) {
            const unsigned short* q = xp + (t + 2) * G3;
            pxrz[cur] = bf2f(q[lane]);
            pxn[cur]  = bf2f(q[64 + h]);
        }

        // broadcast h[0..31] from lanes 0..31 into SGPRs (VALU pipe)
        float hv[32];
        #pragma unroll
        for (int k = 0; k < 32; ++k)
            hv[k] = __int_as_float(__builtin_amdgcn_readlane(__float_as_int(hstate), k));

        // matvec: one stream covers r (lower) + z (upper); n in both halves.
        float a0 = brz, a1 = 0.f, n0 = bn, n1 = 0.f;
        #pragma unroll
        for (int k = 0; k < 32; k += 2) {
            a0 += wrz[k]     * hv[k];
            n0 += wn[k]      * hv[k];
            a1 += wrz[k + 1] * hv[k + 1];
            n1 += wn[k + 1]  * hv[k + 1];
        }
        float pre = cxrz + a0 + a1;        // lane<32: r-pre; lane>=32: z-pre
        float hn  = n0 + n1;

        float sig = 1.f / (1.f + exp2f(-LOG2E * pre));
        float zv  = __shfl_xor(sig, 32, 64);   // lanes<32 receive z

        float a  = cxn + sig * hn;             // lanes<32: uses r=sig
        float tt = exp2f(-2.f * LOG2E * fabsf(a));
        float th = copysignf((1.f - tt) / (1.f + tt), a);
        hstate = (1.f - zv) * th + zv * hstate;
    }

    // head: valid h in lanes 0-31
    float v = (lane < 32) ? hstate * W_head[h] : 0.f;
    #pragma unroll
    for (int s = 32; s >= 1; s >>= 1) v += __shfl_xor(v, s, 64);
    if (lane == 0) out[b] = 1.f / (1.f + exp2f(-LOG2E * (v + b_head[0])));
}

extern "C" void kernel_launch(void* const* d_in, const int* in_sizes, int n_in,
                              void* d_out, int out_size, void* d_ws, size_t ws_size,
                              hipStream_t stream)
{
    const float* x      = (const float*)d_in[0];
    const float* W_ih   = (const float*)d_in[1];
    const float* W_hh   = (const float*)d_in[2];
    const float* b_ih   = (const float*)d_in[3];
    const float* b_hh   = (const float*)d_in[4];
    const float* W_head = (const float*)d_in[5];
    const float* b_head = (const float*)d_in[6];
    float* out = (float*)d_out;

    unsigned short* xg = (unsigned short*)d_ws;   // bf16 xg, 96 MB

    proj_mfma32<<<512, 256, 0, stream>>>(x, W_ih, b_ih, xg);
    gru_scan<<<512, 256, 0, stream>>>(xg, W_hh, b_hh, W_head, b_head, out);
}

// Round 4
// 347.712 us; speedup vs baseline: 1.2507x; 1.1456x over previous
//
#include <hip/hip_runtime.h>
#include <cstdint>

// GRU: B=2048, T=256, F=64, H=32. fp32 in/out.
// Phase 1 (proj16): xg = x@W_ih^T + fold  via 16x16x32 bf16 MFMA (hi/lo A&B,
//   3-term products = fp32-quality). Stored bf16, layout [t][b][pos] with
//   pos = m*6+nt  (gate g = 16*nt+m), fold = b_ih (+ b_hh for r,z gates).
// Phase 2 (gru16): per-step matvec on the MATRIX pipe. 1 wave = 4 batches,
//   A rows replicated (row r -> batch r&3); 6 MFMAs/step give all 96 gate
//   pre-acts for 4 batches; quad q owns batch q's activations; h (bf16)
//   round-trips 256B LDS to re-enter A layout. Head fused.

#define BATCH 2048
#define TSEQ  256

typedef __attribute__((ext_vector_type(8))) short bf16x8;
typedef __attribute__((ext_vector_type(4))) float f32x4;

__device__ __forceinline__ short f2bf(float f) {
    union { float f; unsigned u; } v; v.f = f;
    unsigned r = (v.u + 0x7fffu + ((v.u >> 16) & 1u)) >> 16;
    return (short)r;
}
__device__ __forceinline__ float bfs2f(short s) {
    union { unsigned u; float f; } v; v.u = ((unsigned)(unsigned short)s) << 16;
    return v.f;
}
__device__ __forceinline__ float bf2f_lo(unsigned u) {
    union { unsigned u; float f; } v; v.u = u << 16; return v.f;
}
__device__ __forceinline__ float bf2f_hi(unsigned u) {
    union { unsigned u; float f; } v; v.u = u & 0xffff0000u; return v.f;
}
__device__ __forceinline__ float sel4(f32x4 v, int q) {
    float x = (q & 1) ? v.y : v.x;
    float y = (q & 1) ? v.w : v.z;
    return (q & 2) ? y : x;
}

// ---------------- Phase 1: projection (HBM-bound target) --------------------
// 512 blocks x 256 thr = 2048 waves; wave w = batch w; 16 iters x 16 t-rows.
__global__ __launch_bounds__(256, 2)
void proj16(const float* __restrict__ x, const float* __restrict__ W_ih,
            const float* __restrict__ b_ih, const float* __restrict__ b_hh,
            unsigned* __restrict__ xg)
{
    const int tid  = threadIdx.x;
    const int b    = blockIdx.x * 4 + (tid >> 6);
    const int lane = tid & 63;
    const int m    = lane & 15;
    const int q    = lane >> 4;

    // B frags: [nt][ks], hi & lo  (96 VGPR)
    bf16x8 Bh[12], Bl[12];
    #pragma unroll
    for (int nt = 0; nt < 6; ++nt)
        #pragma unroll
        for (int ks = 0; ks < 2; ++ks) {
            const float* wp = W_ih + (nt * 16 + m) * 64 + ks * 32 + q * 8;
            float4 w0 = ((const float4*)wp)[0], w1 = ((const float4*)wp)[1];
            float wv[8] = {w0.x,w0.y,w0.z,w0.w, w1.x,w1.y,w1.z,w1.w};
            bf16x8 hh, ll;
            #pragma unroll
            for (int j = 0; j < 8; ++j) {
                short h = f2bf(wv[j]);
                hh[j] = h;
                ll[j] = f2bf(wv[j] - bfs2f(h));
            }
            Bh[nt * 2 + ks] = hh;
            Bl[nt * 2 + ks] = ll;
        }
    float fold[6];
    #pragma unroll
    for (int nt = 0; nt < 6; ++nt) {
        int g = nt * 16 + m;
        fold[nt] = b_ih[g] + (nt < 4 ? b_hh[g] : 0.f);   // b_hn handled in phase 2
    }

    const float* xb = x + (size_t)b * TSEQ * 64;
    float4 raw[4];
    {
        const float* p = xb + m * 64 + q * 8;
        raw[0] = ((const float4*)p)[0];        raw[1] = ((const float4*)p)[1];
        raw[2] = ((const float4*)(p + 32))[0]; raw[3] = ((const float4*)(p + 32))[1];
    }

    for (int i = 0; i < 16; ++i) {
        float av[16] = {raw[0].x,raw[0].y,raw[0].z,raw[0].w,
                        raw[1].x,raw[1].y,raw[1].z,raw[1].w,
                        raw[2].x,raw[2].y,raw[2].z,raw[2].w,
                        raw[3].x,raw[3].y,raw[3].z,raw[3].w};
        bf16x8 Ah[2], Al[2];
        #pragma unroll
        for (int ks = 0; ks < 2; ++ks)
            #pragma unroll
            for (int j = 0; j < 8; ++j) {
                float v = av[ks * 8 + j];
                short h = f2bf(v);
                Ah[ks][j] = h;
                Al[ks][j] = f2bf(v - bfs2f(h));
            }
        // prefetch next iter (raw dead after conversion above)
        {
            int inext = (i < 15) ? i + 1 : 15;
            const float* p = xb + (inext * 16 + m) * 64 + q * 8;
            raw[0] = ((const float4*)p)[0];        raw[1] = ((const float4*)p)[1];
            raw[2] = ((const float4*)(p + 32))[0]; raw[3] = ((const float4*)(p + 32))[1];
        }

        f32x4 acc[6];
        #pragma unroll
        for (int nt = 0; nt < 6; ++nt) acc[nt] = (f32x4){0.f,0.f,0.f,0.f};
        #pragma unroll
        for (int ks = 0; ks < 2; ++ks)
            #pragma unroll
            for (int nt = 0; nt < 6; ++nt) {
                acc[nt] = __builtin_amdgcn_mfma_f32_16x16x32_bf16(Ah[ks], Bh[nt*2+ks], acc[nt], 0, 0, 0);
                acc[nt] = __builtin_amdgcn_mfma_f32_16x16x32_bf16(Al[ks], Bh[nt*2+ks], acc[nt], 0, 0, 0);
                acc[nt] = __builtin_amdgcn_mfma_f32_16x16x32_bf16(Ah[ks], Bl[nt*2+ks], acc[nt], 0, 0, 0);
            }

        // epilogue: C row = q*4+reg -> t = 16i+4q+reg; pack (nt even, nt odd)
        #pragma unroll
        for (int reg = 0; reg < 4; ++reg) {
            int t = i * 16 + q * 4 + reg;
            size_t T = (size_t)t * BATCH + b;
            unsigned* dst = xg + T * 48 + m * 3;
            float v0 = acc[0][reg] + fold[0], v1 = acc[1][reg] + fold[1];
            float v2 = acc[2][reg] + fold[2], v3 = acc[3][reg] + fold[3];
            float v4 = acc[4][reg] + fold[4], v5 = acc[5][reg] + fold[5];
            dst[0] = (unsigned)(unsigned short)f2bf(v0) | ((unsigned)(unsigned short)f2bf(v1) << 16);
            dst[1] = (unsigned)(unsigned short)f2bf(v2) | ((unsigned)(unsigned short)f2bf(v3) << 16);
            dst[2] = (unsigned)(unsigned short)f2bf(v4) | ((unsigned)(unsigned short)f2bf(v5) << 16);
        }
    }
}

// ---------------- Phase 2: MFMA recurrence ----------------------------------
// 512 blocks x 64 thr (1 wave); wave = 4 batches; quad q owns batch b0+q.
struct U3 { unsigned a, b, c; };

__global__ __launch_bounds__(64, 2)
void gru16(const unsigned* __restrict__ xg, const float* __restrict__ W_hh,
           const float* __restrict__ b_hh, const float* __restrict__ W_head,
           const float* __restrict__ b_head, float* __restrict__ out)
{
    __shared__ unsigned short hbuf[128];     // [b][d] bf16: idx = b*32 + d
    const int lane = threadIdx.x;
    const int m = lane & 15;
    const int q = lane >> 4;
    const int b = blockIdx.x * 4 + q;        // batch owned by this quad

    // W_hh B-frags: tile nt covers gates 16nt+m; K=32 in one MFMA
    bf16x8 Bw[6];
    #pragma unroll
    for (int nt = 0; nt < 6; ++nt) {
        const float* wp = W_hh + (nt * 16 + m) * 32 + q * 8;
        float4 w0 = ((const float4*)wp)[0], w1 = ((const float4*)wp)[1];
        float wv[8] = {w0.x,w0.y,w0.z,w0.w, w1.x,w1.y,w1.z,w1.w};
        bf16x8 hh;
        #pragma unroll
        for (int j = 0; j < 8; ++j) hh[j] = f2bf(wv[j]);
        Bw[nt] = hh;
    }
    const float bn0 = b_hh[64 + m];          // b_hn for d=m
    const float bn1 = b_hh[80 + m];          // b_hn for d=m+16

    ((unsigned*)hbuf)[lane] = 0u;            // h0 = 0
    __syncthreads();

    const unsigned* base = xg + (size_t)b * 48 + m * 3;   // + t*BATCH*48
    U3 s0, s1, s2, s3;
    #define LD(T_) { const unsigned* p = base + (size_t)(T_) * (BATCH * 48); \
                     tmp.a = p[0]; tmp.b = p[1]; tmp.c = p[2]; }
    { U3 tmp; LD(0) s0 = tmp; LD(1) s1 = tmp; LD(2) s2 = tmp; LD(3) s3 = tmp; }

    float h0 = 0.f, h1 = 0.f;                // h[b][m], h[b][m+16] fp32
    const float L2E = 1.4426950408889634f;

    auto body = [&](U3& S, int tpre) {
        // A frag: rows replicated -> row beta holds h[beta&3]
        bf16x8 A = *(const bf16x8*)&hbuf[(m & 3) * 32 + q * 8];
        unsigned ca = S.a, cb = S.b, cc = S.c;
        { U3 tmp; LD(tpre) S = tmp; }        // refill slot (t+4)

        f32x4 zz = (f32x4){0.f,0.f,0.f,0.f};
        f32x4 a0 = __builtin_amdgcn_mfma_f32_16x16x32_bf16(A, Bw[0], zz, 0, 0, 0);
        f32x4 a1 = __builtin_amdgcn_mfma_f32_16x16x32_bf16(A, Bw[1], zz, 0, 0, 0);
        f32x4 a2 = __builtin_amdgcn_mfma_f32_16x16x32_bf16(A, Bw[2], zz, 0, 0, 0);
        f32x4 a3 = __builtin_amdgcn_mfma_f32_16x16x32_bf16(A, Bw[3], zz, 0, 0, 0);
        f32x4 a4 = __builtin_amdgcn_mfma_f32_16x16x32_bf16(A, Bw[4], zz, 0, 0, 0);
        f32x4 a5 = __builtin_amdgcn_mfma_f32_16x16x32_bf16(A, Bw[5], zz, 0, 0, 0);

        float xr0 = bf2f_lo(ca), xr1 = bf2f_hi(ca);
        float xz0 = bf2f_lo(cb), xz1 = bf2f_hi(cb);
        float xn0 = bf2f_lo(cc), xn1 = bf2f_hi(cc);

        float pr0 = sel4(a0, q), pr1 = sel4(a1, q);
        float pz0 = sel4(a2, q), pz1 = sel4(a3, q);
        float pn0 = sel4(a4, q), pn1 = sel4(a5, q);

        float r0 = 1.f / (1.f + exp2f(-L2E * (xr0 + pr0)));
        float r1 = 1.f / (1.f + exp2f(-L2E * (xr1 + pr1)));
        float z0 = 1.f / (1.f + exp2f(-L2E * (xz0 + pz0)));
        float z1 = 1.f / (1.f + exp2f(-L2E * (xz1 + pz1)));
        float n0 = xn0 + r0 * (pn0 + bn0);
        float n1 = xn1 + r1 * (pn1 + bn1);
        float e0 = exp2f(-2.f * L2E * fabsf(n0));
        float e1 = exp2f(-2.f * L2E * fabsf(n1));
        float t0 = copysignf((1.f - e0) / (1.f + e0), n0);
        float t1 = copysignf((1.f - e1) / (1.f + e1), n1);
        h0 = t0 + z0 * (h0 - t0);
        h1 = t1 + z1 * (h1 - t1);

        hbuf[q * 32 + m]      = (unsigned short)f2bf(h0);
        hbuf[q * 32 + 16 + m] = (unsigned short)f2bf(h1);
    };

    for (int t = 0; t < TSEQ; t += 4) {
        body(s0, (t + 4 < TSEQ) ? t + 4 : TSEQ - 1);
        body(s1, (t + 5 < TSEQ) ? t + 5 : TSEQ - 1);
        body(s2, (t + 6 < TSEQ) ? t + 6 : TSEQ - 1);
        body(s3, (t + 7 < TSEQ) ? t + 7 : TSEQ - 1);
    }
    #undef LD

    // head: reduce 32 dims held as 2/lane across the 16 lanes of this quad
    float v = h0 * W_head[m] + h1 * W_head[16 + m];
    v += __shfl_xor(v, 1, 64);
    v += __shfl_xor(v, 2, 64);
    v += __shfl_xor(v, 4, 64);
    v += __shfl_xor(v, 8, 64);
    if (m == 0) out[b] = 1.f / (1.f + exp2f(-L2E * (v + b_head[0])));
}

extern "C" void kernel_launch(void* const* d_in, const int* in_sizes, int n_in,
                              void* d_out, int out_size, void* d_ws, size_t ws_size,
                              hipStream_t stream)
{
    const float* x      = (const float*)d_in[0];
    const float* W_ih   = (const float*)d_in[1];
    const float* W_hh   = (const float*)d_in[2];
    const float* b_ih   = (const float*)d_in[3];
    const float* b_hh   = (const float*)d_in[4];
    const float* W_head = (const float*)d_in[5];
    const float* b_head = (const float*)d_in[6];
    float* out = (float*)d_out;

    unsigned* xg = (unsigned*)d_ws;   // bf16 xg, [t][b][96] permuted, ~100 MB

    proj16<<<512, 256, 0, stream>>>(x, W_ih, b_ih, b_hh, xg);
    gru16<<<512, 64, 0, stream>>>(xg, W_hh, b_hh, W_head, b_head, out);
}

// Round 5
// 312.466 us; speedup vs baseline: 1.3917x; 1.1128x over previous
//
#include <hip/hip_runtime.h>
#include <cstdint>

// Fully-fused GRU: B=2048, T=256, F=64, H=32. fp32 in/out. ONE kernel.
// 512 blocks x 64 thr (1 wave); wave = 4 batches (batch = quad q).
// Per step t:
//   x-proj: pre[g] += x[b][t][:]·W_ih[g,:]  -- 24 MFMA (2 k-chunks x hi/lo x),
//           off the serial chain (x is h-independent, prefetched 4 deep).
//   hh:     pre[g] += h·W_hh[g,:]           -- 6 MFMA chained on the x-acc.
//   A rows replicated row->batch row>>2: every C reg of a lane = its quad's
//   batch -> extraction is acc[nt][0], no cndmask.
//   h (bf16, K-permuted pairs) round-trips 256B LDS: 1 ds_write_b32 + 1
//   ds_read_b128 per step. Head fused at the end.

#define BATCH 2048
#define TSEQ  256

typedef __attribute__((ext_vector_type(8))) short bf16x8;
typedef __attribute__((ext_vector_type(4))) float f32x4;

union BF8 { unsigned u[4]; bf16x8 v; };

// rounded bf16 bits of f, positioned in the HIGH 16 bits (RNE)
__device__ __forceinline__ unsigned bfr(float f) {
    unsigned u = __float_as_uint(f);
    return u + 0x7fffu + ((u >> 16) & 1u);
}
__device__ __forceinline__ short bfs(float f) {        // init-time scalar bf16
    return (short)(bfr(f) >> 16);
}
// pack hi16(a)->low half, hi16(b)->high half
__device__ __forceinline__ unsigned packhi(unsigned ua, unsigned ub) {
    return __builtin_amdgcn_perm(ub, ua, 0x07060302u);
}

// 8 fp32 -> hi bf16x8 (truncated) + lo bf16x8 (residual, exact to 2^-17)
__device__ __forceinline__ void cvt2(const float4& f0, const float4& f1,
                                     bf16x8& hi, bf16x8& lo) {
    float f[8] = {f0.x, f0.y, f0.z, f0.w, f1.x, f1.y, f1.z, f1.w};
    BF8 H, L;
    #pragma unroll
    for (int d = 0; d < 4; ++d) {
        float a = f[2 * d], b = f[2 * d + 1];
        unsigned ua = __float_as_uint(a), ub = __float_as_uint(b);
        float ra = a - __uint_as_float(ua & 0xffff0000u);
        float rb = b - __uint_as_float(ub & 0xffff0000u);
        H.u[d] = packhi(ua, ub);
        L.u[d] = packhi(__float_as_uint(ra), __float_as_uint(rb));
    }
    hi = H.v; lo = L.v;
}

__global__ __launch_bounds__(64, 1)
void gru_fused(const float* __restrict__ x, const float* __restrict__ W_ih,
               const float* __restrict__ W_hh, const float* __restrict__ b_ih,
               const float* __restrict__ b_hh, const float* __restrict__ W_head,
               const float* __restrict__ b_head, float* __restrict__ out)
{
    __shared__ __align__(16) unsigned hbuf[64];   // [batch][dim-pair] bf16x2
    const int lane = threadIdx.x;
    const int m = lane & 15;
    const int q = lane >> 4;                      // quad == this lane's batch
    const int b0 = blockIdx.x * 4;

    // ---- W_ih B-frags (plain bf16): [nt][chunk], elem j = W[nt*16+m][c*32+q*8+j]
    bf16x8 Bx[6][2];
    #pragma unroll
    for (int nt = 0; nt < 6; ++nt)
        #pragma unroll
        for (int c = 0; c < 2; ++c) {
            const float* wp = W_ih + (nt * 16 + m) * 64 + c * 32 + q * 8;
            BF8 t;
            #pragma unroll
            for (int d = 0; d < 4; ++d)
                t.u[d] = packhi(bfr(wp[2 * d]) & 0xffff0000u,
                                bfr(wp[2 * d + 1]) & 0xffff0000u);
            Bx[nt][c] = t.v;
        }

    // ---- W_hh B-frags, K-permuted: position p=q*8+j -> dim (p>>1)+16*(p&1)
    bf16x8 Bw[6];
    #pragma unroll
    for (int nt = 0; nt < 6; ++nt) {
        const float* wp = W_hh + (nt * 16 + m) * 32;
        BF8 t;
        #pragma unroll
        for (int d = 0; d < 4; ++d) {
            int p0 = q * 8 + 2 * d, p1 = p0 + 1;
            int d0 = (p0 >> 1) + ((p0 & 1) << 4);
            int d1 = (p1 >> 1) + ((p1 & 1) << 4);
            t.u[d] = packhi(bfr(wp[d0]) & 0xffff0000u, bfr(wp[d1]) & 0xffff0000u);
        }
        Bw[nt] = t.v;
    }

    // ---- biases
    const float fr0 = b_ih[m]      + b_hh[m];
    const float fr1 = b_ih[16 + m] + b_hh[16 + m];
    const float fz0 = b_ih[32 + m] + b_hh[32 + m];
    const float fz1 = b_ih[48 + m] + b_hh[48 + m];
    const float fn0 = b_ih[64 + m];
    const float fn1 = b_ih[80 + m];
    const float bn0 = b_hh[64 + m], bn1 = b_hh[80 + m];
    const f32x4 Z   = (f32x4){0.f, 0.f, 0.f, 0.f};
    const f32x4 BN0 = (f32x4){bn0, bn0, bn0, bn0};
    const f32x4 BN1 = (f32x4){bn1, bn1, bn1, bn1};

    // ---- h = 0
    hbuf[lane] = 0u;
    float h0 = 0.f, h1 = 0.f;                     // h[batch q][m], [m+16]
    unsigned* hw = hbuf + q * 16 + m;             // write slot (b32: dims m|m+16)
    const bf16x8* ard = (const bf16x8*)((const char*)hbuf + (m >> 2) * 64 + q * 16);

    // ---- x prefetch ring, depth 4: 16 floats/lane/step (4-way lane-replicated)
    const float* xb = x + ((size_t)(b0 + (m >> 2))) * (TSEQ * 64) + q * 8;
    float4 px[4][4];
    #pragma unroll
    for (int s = 0; s < 4; ++s) {
        const float* p = xb + s * 64;
        px[s][0] = ((const float4*)p)[0];        px[s][1] = ((const float4*)p)[1];
        px[s][2] = ((const float4*)(p + 32))[0]; px[s][3] = ((const float4*)(p + 32))[1];
    }

    const float L2E = 1.4426950408889634f;

    auto step = [&](float4* S, int tpre) {
        // convert current x (hi/lo), then refill the slot
        bf16x8 Ah0, Al0, Ah1, Al1;
        cvt2(S[0], S[1], Ah0, Al0);
        cvt2(S[2], S[3], Ah1, Al1);
        {
            const float* p = xb + tpre * 64;
            S[0] = ((const float4*)p)[0];        S[1] = ((const float4*)p)[1];
            S[2] = ((const float4*)(p + 32))[0]; S[3] = ((const float4*)(p + 32))[1];
        }
        // h -> A frag (LDS round-trip)
        bf16x8 Ahh = *ard;

        // x-projection (off-chain) then hh chained on top
        f32x4 acc[6];
        #pragma unroll
        for (int nt = 0; nt < 6; ++nt) {
            acc[nt] = __builtin_amdgcn_mfma_f32_16x16x32_bf16(Ah0, Bx[nt][0], Z, 0, 0, 0);
            acc[nt] = __builtin_amdgcn_mfma_f32_16x16x32_bf16(Al0, Bx[nt][0], acc[nt], 0, 0, 0);
            acc[nt] = __builtin_amdgcn_mfma_f32_16x16x32_bf16(Ah1, Bx[nt][1], acc[nt], 0, 0, 0);
            acc[nt] = __builtin_amdgcn_mfma_f32_16x16x32_bf16(Al1, Bx[nt][1], acc[nt], 0, 0, 0);
        }
        #pragma unroll
        for (int nt = 0; nt < 4; ++nt)
            acc[nt] = __builtin_amdgcn_mfma_f32_16x16x32_bf16(Ahh, Bw[nt], acc[nt], 0, 0, 0);
        f32x4 an0 = __builtin_amdgcn_mfma_f32_16x16x32_bf16(Ahh, Bw[4], BN0, 0, 0, 0);
        f32x4 an1 = __builtin_amdgcn_mfma_f32_16x16x32_bf16(Ahh, Bw[5], BN1, 0, 0, 0);

        // activations: every C reg of this lane = batch q -> use [0]
        float rr0 = 1.f / (1.f + exp2f(-L2E * (acc[0][0] + fr0)));
        float rr1 = 1.f / (1.f + exp2f(-L2E * (acc[1][0] + fr1)));
        float zz0 = 1.f / (1.f + exp2f(-L2E * (acc[2][0] + fz0)));
        float zz1 = 1.f / (1.f + exp2f(-L2E * (acc[3][0] + fz1)));
        float a0 = acc[4][0] + fn0 + rr0 * an0[0];
        float a1 = acc[5][0] + fn1 + rr1 * an1[0];
        float e0 = exp2f(-2.f * L2E * fabsf(a0));
        float e1 = exp2f(-2.f * L2E * fabsf(a1));
        float t0 = copysignf((1.f - e0) / (1.f + e0), a0);
        float t1 = copysignf((1.f - e1) / (1.f + e1), a1);
        h0 = t0 + zz0 * (h0 - t0);
        h1 = t1 + zz1 * (h1 - t1);

        *hw = packhi(bfr(h0), bfr(h1));          // dims m (lo) | m+16 (hi)
    };

    for (int t = 0; t < TSEQ; t += 4) {
        #pragma unroll
        for (int s = 0; s < 4; ++s) {
            int tp = t + 4 + s;
            if (tp > TSEQ - 1) tp = TSEQ - 1;
            step(px[s], tp);
        }
    }

    // ---- head: y = sigmoid(h · W_head + b); reduce 16 m-lanes within quad
    float v = h0 * W_head[m] + h1 * W_head[16 + m];
    v += __shfl_xor(v, 1, 64);
    v += __shfl_xor(v, 2, 64);
    v += __shfl_xor(v, 4, 64);
    v += __shfl_xor(v, 8, 64);
    if (m == 0) out[b0 + q] = 1.f / (1.f + exp2f(-L2E * (v + b_head[0])));
}

extern "C" void kernel_launch(void* const* d_in, const int* in_sizes, int n_in,
                              void* d_out, int out_size, void* d_ws, size_t ws_size,
                              hipStream_t stream)
{
    const float* x      = (const float*)d_in[0];
    const float* W_ih   = (const float*)d_in[1];
    const float* W_hh   = (const float*)d_in[2];
    const float* b_ih   = (const float*)d_in[3];
    const float* b_hh   = (const float*)d_in[4];
    const float* W_head = (const float*)d_in[5];
    const float* b_head = (const float*)d_in[6];
    float* out = (float*)d_out;

    gru_fused<<<BATCH / 4, 64, 0, stream>>>(x, W_ih, W_hh, b_ih, b_hh,
                                            W_head, b_head, out);
}

// Round 6
// 288.549 us; speedup vs baseline: 1.5071x; 1.0829x over previous
//
#include <hip/hip_runtime.h>
#include <cstdint>

// Fully-fused GRU: B=2048, T=256, F=64, H=32. fp32 in/out. ONE kernel.
// 512 blocks x 64 thr (1 wave = 4 batches). Groups of 4 timesteps:
//   x-proj (24 MFMA / group, A=W_ih, B=x hi/lo): C cols = (batch m&3, step m>>2),
//     rows = gates -> dumped to LDS (double-buffered 6KB), act-lanes prefetch
//     their 24 scalars per group at group top (off-chain).
//   per step: 6 hh MFMAs (A=W_hh K-permuted, B=h bf16, C-init = folded biases),
//     zero-redundancy acts (lane owns dims (q*4+(m>>2), +16) of batch m&3),
//     h exchange via 8 static-index shuffles (no LDS round-trip on the chain),
//     h carried fp32 in-lane. Head fused.

#define TSEQ 256

typedef __attribute__((ext_vector_type(8))) short bf16x8;
typedef __attribute__((ext_vector_type(4))) float f32x4;
union BF8 { unsigned u[4]; bf16x8 v; };

__device__ __forceinline__ unsigned bfr(float f) {            // bf16 RNE in hi16
    unsigned u = __float_as_uint(f);
    return u + 0x7fffu + ((u >> 16) & 1u);
}
__device__ __forceinline__ unsigned packhi(unsigned a, unsigned b) {
    return __builtin_amdgcn_perm(b, a, 0x07060302u);          // hi16(a)|hi16(b)<<16
}
// 8 fp32 -> hi (truncated bf16) + lo (bf16 of residual): 3-term-quality products
__device__ __forceinline__ void cvt2(const float4& f0, const float4& f1,
                                     bf16x8& hi, bf16x8& lo) {
    float f[8] = {f0.x,f0.y,f0.z,f0.w, f1.x,f1.y,f1.z,f1.w};
    BF8 H, L;
    #pragma unroll
    for (int d = 0; d < 4; ++d) {
        float a = f[2*d], b = f[2*d+1];
        unsigned ua = __float_as_uint(a), ub = __float_as_uint(b);
        float ra = a - __uint_as_float(ua & 0xffff0000u);
        float rb = b - __uint_as_float(ub & 0xffff0000u);
        H.u[d] = packhi(ua, ub);
        L.u[d] = packhi(bfr(ra), bfr(rb));
    }
    hi = H.v; lo = L.v;
}
__device__ __forceinline__ float sel4(f32x4 v, int u) {
    float a = (u & 1) ? v[1] : v[0];
    float b = (u & 1) ? v[3] : v[2];
    return (u & 2) ? b : a;
}
__device__ __forceinline__ float sigx(float v) {
    return __builtin_amdgcn_rcpf(1.f + exp2f(-1.4426950408889634f * v));
}
__device__ __forceinline__ float tanhx(float v) {
    float e = exp2f(-2.8853900817779268f * fabsf(v));
    return copysignf((1.f - e) * __builtin_amdgcn_rcpf(1.f + e), v);
}

#define MFMA16(A, B, C) __builtin_amdgcn_mfma_f32_16x16x32_bf16((A), (B), (C), 0, 0, 0)

__global__ __launch_bounds__(64, 1)
void gru_fused(const float* __restrict__ x, const float* __restrict__ W_ih,
               const float* __restrict__ W_hh, const float* __restrict__ b_ih,
               const float* __restrict__ b_hh, const float* __restrict__ W_head,
               const float* __restrict__ b_head, float* __restrict__ out)
{
    __shared__ float xsh[2][1536];                 // [buf][lane*24 + nt*4 + reg]
    const int lane = threadIdx.x;
    const int m = lane & 15, q = lane >> 4;
    const int bq = m & 3, u = m >> 2;              // batch-in-wave, step/dim-shard
    const int b0 = blockIdx.x * 4;

    // ---- W_ih A-frags (plain bf16): A[m][c*32+q*8+j] = W_ih[nt*16+m][...]
    bf16x8 Aih[6][2];
    #pragma unroll
    for (int nt = 0; nt < 6; ++nt)
        #pragma unroll
        for (int c = 0; c < 2; ++c) {
            const float* wp = W_ih + (nt*16 + m)*64 + c*32 + q*8;
            BF8 t;
            #pragma unroll
            for (int d = 0; d < 4; ++d) t.u[d] = packhi(bfr(wp[2*d]), bfr(wp[2*d+1]));
            Aih[nt][c] = t.v;
        }

    // ---- W_hh A-frags, K-permuted: pos p=q*8+j <-> dim (p>>1)+16*(p&1)
    bf16x8 Awh[6];
    #pragma unroll
    for (int nt = 0; nt < 6; ++nt) {
        const float* wp = W_hh + (nt*16 + m)*32;
        BF8 t;
        #pragma unroll
        for (int d = 0; d < 4; ++d) {
            int dd = q*4 + d;
            t.u[d] = packhi(bfr(wp[dd]), bfr(wp[dd + 16]));
        }
        Awh[nt] = t.v;
    }

    // ---- biases: C-init vectors (component reg <-> gate nt*16+q*4+reg)
    f32x4 FRZ[4], BN0, BN1;
    #pragma unroll
    for (int nt = 0; nt < 4; ++nt) {
        f32x4 t;
        #pragma unroll
        for (int r = 0; r < 4; ++r) { int g = nt*16 + q*4 + r; t[r] = b_ih[g] + b_hh[g]; }
        FRZ[nt] = t;
    }
    #pragma unroll
    for (int r = 0; r < 4; ++r) { BN0[r] = b_hh[64+q*4+r]; BN1[r] = b_hh[80+q*4+r]; }
    const float fn0 = b_ih[64 + q*4 + u], fn1 = b_ih[80 + q*4 + u];

    // ---- x column for this lane: (batch b0+bq, t = 4*grp + u), cols q*8..q*8+7
    const float* xcol = x + ((size_t)(b0 + bq)*TSEQ + u)*64 + q*8;
    float4 ring[4];
    auto ldring = [&](int grp) {
        const float* p = xcol + grp*256;           // grp*4 steps * 64 floats
        ring[0] = ((const float4*)p)[0];        ring[1] = ((const float4*)p)[1];
        ring[2] = ((const float4*)(p+32))[0];   ring[3] = ((const float4*)(p+32))[1];
    };
    auto projwrite = [&](int buf) {                // ring -> xacc -> LDS[buf]
        bf16x8 Xh0, Xl0, Xh1, Xl1;
        cvt2(ring[0], ring[1], Xh0, Xl0);
        cvt2(ring[2], ring[3], Xh1, Xl1);
        #pragma unroll
        for (int nt = 0; nt < 6; ++nt) {
            f32x4 a = MFMA16(Aih[nt][0], Xh0, ((f32x4){0.f,0.f,0.f,0.f}));
            a = MFMA16(Aih[nt][0], Xl0, a);
            a = MFMA16(Aih[nt][1], Xh1, a);
            a = MFMA16(Aih[nt][1], Xl1, a);
            *(f32x4*)&xsh[buf][lane*24 + nt*4] = a;
        }
    };

    ldring(0);
    projwrite(0);
    ldring(1);

    unsigned Hd[4] = {0u, 0u, 0u, 0u};             // h B-frag dwords (bf16 pairs)
    float hOL = 0.f, hOH = 0.f;                    // own h dims (q*4+u, +16), fp32

    for (int g = 0; g < 64; ++g) {
        const int cbuf = g & 1, nbuf = cbuf ^ 1;
        // prefetch this group's x-pre scalars (24 ds_read_b32, off-chain)
        float xp[4][6];
        #pragma unroll
        for (int s = 0; s < 4; ++s) {
            const float* rp = &xsh[cbuf][(q*16 + bq + 4*s)*24 + u];
            #pragma unroll
            for (int nt = 0; nt < 6; ++nt) xp[s][nt] = rp[nt*4];
        }
        // next group's projection + ring refill (off-chain)
        projwrite(nbuf);
        ldring(g + 2 < 64 ? g + 2 : 63);

        #pragma unroll
        for (int s = 0; s < 4; ++s) {
            BF8 bh; bh.u[0]=Hd[0]; bh.u[1]=Hd[1]; bh.u[2]=Hd[2]; bh.u[3]=Hd[3];
            f32x4 a0 = MFMA16(Awh[0], bh.v, FRZ[0]);
            f32x4 a1 = MFMA16(Awh[1], bh.v, FRZ[1]);
            f32x4 a2 = MFMA16(Awh[2], bh.v, FRZ[2]);
            f32x4 a3 = MFMA16(Awh[3], bh.v, FRZ[3]);
            f32x4 a4 = MFMA16(Awh[4], bh.v, BN0);
            f32x4 a5 = MFMA16(Awh[5], bh.v, BN1);

            float r0 = sigx(xp[s][0] + sel4(a0, u));
            float r1 = sigx(xp[s][1] + sel4(a1, u));
            float z0 = sigx(xp[s][2] + sel4(a2, u));
            float z1 = sigx(xp[s][3] + sel4(a3, u));
            float t0 = tanhx(xp[s][4] + fn0 + r0 * sel4(a4, u));
            float t1 = tanhx(xp[s][5] + fn1 + r1 * sel4(a5, u));
            float hNL = t0 + z0 * (hOL - t0);
            float hNH = t1 + z1 * (hOH - t1);
            hOL = hNL; hOH = hNH;

            // rebuild B-frag: dims (q*4+w, +16) of batch bq from lane 16q+bq+4w
            #pragma unroll
            for (int w = 0; w < 4; ++w) {
                int src = (q << 4) + bq + (w << 2);
                float hl  = __shfl(hNL, src, 64);
                float hh2 = __shfl(hNH, src, 64);
                Hd[w] = packhi(bfr(hl), bfr(hh2));
            }
        }
    }

    // ---- head: lane holds fp32 h dims (q*4+u, +16) of batch bq
    float v = hOL * W_head[q*4 + u] + hOH * W_head[16 + q*4 + u];
    v += __shfl_xor(v, 4, 64);
    v += __shfl_xor(v, 8, 64);
    v += __shfl_xor(v, 16, 64);
    v += __shfl_xor(v, 32, 64);
    if (lane < 4) out[b0 + lane] = sigx(v + b_head[0]);
}

extern "C" void kernel_launch(void* const* d_in, const int* in_sizes, int n_in,
                              void* d_out, int out_size, void* d_ws, size_t ws_size,
                              hipStream_t stream)
{
    const float* x      = (const float*)d_in[0];
    const float* W_ih   = (const float*)d_in[1];
    const float* W_hh   = (const float*)d_in[2];
    const float* b_ih   = (const float*)d_in[3];
    const float* b_hh   = (const float*)d_in[4];
    const float* W_head = (const float*)d_in[5];
    const float* b_head = (const float*)d_in[6];
    float* out = (float*)d_out;

    gru_fused<<<512, 64, 0, stream>>>(x, W_ih, W_hh, b_ih, b_hh,
                                      W_head, b_head, out);
}